// Round 16
// baseline (78.737 us; speedup 1.0000x reference)
//
#include <hip/hip_runtime.h>

typedef _Float16 half8 __attribute__((ext_vector_type(8)));
typedef float f32x4 __attribute__((ext_vector_type(4)));
typedef float f4 __attribute__((ext_vector_type(4)));

#define P_DIM 1024
#define BM 64
#define NH 8          // half-stages of K=128 floats each
#define AF_ROW 132    // LDS A row: 128 floats + 4 pad = 528 B stride (R10-proven)

// FRAGMENT-MAJOR weights (proven R6/R10/R12): B-frag = 64 lanes x 16 B = 1 KB.
// Wf2[((S*4 + t)*64 + l)*8 + j] = W[t*16 + (l&15)][S*32 + (l>>4)*8 + j]
// rows 0-47 = W_w, 48-55 = G_w, 56-63 = 0.  S = k-step 0..31, t = n-tile 0..3.
__global__ __launch_bounds__(256) void prep_weights(
    const float* __restrict__ Gw, const float* __restrict__ Gb,
    const float* __restrict__ Ww, const float* __restrict__ Wb,
    _Float16* __restrict__ Wf2, float* __restrict__ biasC) {
  int i = blockIdx.x * 256 + threadIdx.x;   // 0 .. 65535
  int j = i & 7;
  int l = (i >> 3) & 63;
  int t = (i >> 9) & 3;
  int S = i >> 11;
  int row = t * 16 + (l & 15);
  int k   = S * 32 + (l >> 4) * 8 + j;
  float v = 0.0f;
  if (row < 48) v = Ww[row * P_DIM + k];
  else if (row < 56) v = Gw[(row - 48) * P_DIM + k];
  Wf2[i] = (_Float16)v;
  if (i < 64) {
    float bv = 0.0f;
    if (i < 48) bv = Wb[i];
    else if (i < 56) bv = Gb[i - 48];
    biasC[i] = bv;
  }
}

// BODY chunk cc (0/1 within half-stage): B frags from LDS, A from f32 LDS
// stage + cvt, 8 MFMA with R10's proven pairing. (R12-verbatim)
#define BODY(cc) do { \
    half8 b0_ = *(const half8*)(BsR + (size_t)((2*(cc)  )*4    ) * 1024); \
    half8 b1_ = *(const half8*)(BsR + (size_t)((2*(cc)+1)*4    ) * 1024); \
    half8 b2_ = *(const half8*)(BsR + (size_t)((2*(cc)  )*4 + 1) * 1024); \
    half8 b3_ = *(const half8*)(BsR + (size_t)((2*(cc)+1)*4 + 1) * 1024); \
    f4 a0_[4], a1_[4]; \
    { const char* p0 = Abase0 + (cc) * 256; \
      a0_[0] = *(const f4*)(p0);       a0_[1] = *(const f4*)(p0 + 16); \
      a0_[2] = *(const f4*)(p0 + 128); a0_[3] = *(const f4*)(p0 + 144); \
      const char* p1 = Abase1 + (cc) * 256; \
      a1_[0] = *(const f4*)(p1);       a1_[1] = *(const f4*)(p1 + 16); \
      a1_[2] = *(const f4*)(p1 + 128); a1_[3] = *(const f4*)(p1 + 144); } \
    half8 h00_, h01_, h10_, h11_; \
    h00_[0]=(_Float16)a0_[0][0]; h00_[1]=(_Float16)a0_[0][1]; h00_[2]=(_Float16)a0_[0][2]; h00_[3]=(_Float16)a0_[0][3]; \
    h00_[4]=(_Float16)a0_[1][0]; h00_[5]=(_Float16)a0_[1][1]; h00_[6]=(_Float16)a0_[1][2]; h00_[7]=(_Float16)a0_[1][3]; \
    h01_[0]=(_Float16)a0_[2][0]; h01_[1]=(_Float16)a0_[2][1]; h01_[2]=(_Float16)a0_[2][2]; h01_[3]=(_Float16)a0_[2][3]; \
    h01_[4]=(_Float16)a0_[3][0]; h01_[5]=(_Float16)a0_[3][1]; h01_[6]=(_Float16)a0_[3][2]; h01_[7]=(_Float16)a0_[3][3]; \
    h10_[0]=(_Float16)a1_[0][0]; h10_[1]=(_Float16)a1_[0][1]; h10_[2]=(_Float16)a1_[0][2]; h10_[3]=(_Float16)a1_[0][3]; \
    h10_[4]=(_Float16)a1_[1][0]; h10_[5]=(_Float16)a1_[1][1]; h10_[6]=(_Float16)a1_[1][2]; h10_[7]=(_Float16)a1_[1][3]; \
    h11_[0]=(_Float16)a1_[2][0]; h11_[1]=(_Float16)a1_[2][1]; h11_[2]=(_Float16)a1_[2][2]; h11_[3]=(_Float16)a1_[2][3]; \
    h11_[4]=(_Float16)a1_[3][0]; h11_[5]=(_Float16)a1_[3][1]; h11_[6]=(_Float16)a1_[3][2]; h11_[7]=(_Float16)a1_[3][3]; \
    acc[0] = __builtin_amdgcn_mfma_f32_16x16x32_f16(h00_, b0_, acc[0], 0, 0, 0); \
    acc[0] = __builtin_amdgcn_mfma_f32_16x16x32_f16(h01_, b1_, acc[0], 0, 0, 0); \
    acc[1] = __builtin_amdgcn_mfma_f32_16x16x32_f16(h00_, b2_, acc[1], 0, 0, 0); \
    acc[1] = __builtin_amdgcn_mfma_f32_16x16x32_f16(h01_, b3_, acc[1], 0, 0, 0); \
    acc[2] = __builtin_amdgcn_mfma_f32_16x16x32_f16(h10_, b0_, acc[2], 0, 0, 0); \
    acc[2] = __builtin_amdgcn_mfma_f32_16x16x32_f16(h11_, b1_, acc[2], 0, 0, 0); \
    acc[3] = __builtin_amdgcn_mfma_f32_16x16x32_f16(h10_, b2_, acc[3], 0, 0, 0); \
    acc[3] = __builtin_amdgcn_mfma_f32_16x16x32_f16(h11_, b3_, acc[3], 0, 0, 0); \
  } while (0)

__global__ __launch_bounds__(256, 3) void fused_gate(
    const float* __restrict__ x, const _Float16* __restrict__ Wf2,
    const float* __restrict__ biasC, float* __restrict__ out) {
  // A-stage (f32, R10-proven); epilogue scratch S aliases it per tile.
  __shared__ __align__(16) float Af[BM][AF_ROW];   // 33792 B
  // B-stage: one half-stage's 16 frags, single-buffered (barrier-ordered).
  __shared__ __align__(16) _Float16 BsH[8192];     // 16384 B  (total 50176)

  const int tid  = threadIdx.x;
  const int lane = tid & 63;
  const int w    = tid >> 6;        // wave id 0..3
  const int l15  = lane & 15;
  const int q    = lane >> 4;

  // Wave tile (R10/R12): rows [mrow, mrow+32), cols [ncol, ncol+32)
  const int mrow = (w >> 1) * 32;
  const int ncol = (w & 1) * 32;
  const int tb   = (w & 1) * 2;     // first n-tile of this wave's column pair

  // B global: wave w loads frag-slots w*4..w*4+3 of each half-stage's 16 KB
  const char* bgG = (const char*)Wf2 + (size_t)(w * 4) * 1024 + lane * 16;

  char* Aw = (char*)&Af[w * 16][0] + lane * 8;                 // + i*528 per row
  const char* Abase0 = (const char*)&Af[mrow + l15][0] + q * 32;
  const char* Abase1 = Abase0 + 16 * 528;
  char* BsW = (char*)BsH + (size_t)(w * 4) * 1024 + lane * 16; // + i*1024
  const char* BsR = (const char*)BsH + (size_t)tb * 1024 + lane * 16;
  float (*S)[65] = (float (*)[65])&Af[0][0];   // epilogue scratch aliases Af

  const int r2  = tid >> 2;         // epilogue: 4 threads/row
  const int sub = tid & 3;

  // Two 64-row tiles per block: grid 512 = 2 blocks/CU, ALL co-resident ->
  // zero scheduling tail (R12's grid-1024 left a 256-block second round).
  for (int tile = 0; tile < 2; ++tile) {
    const int row0 = (blockIdx.x * 2 + tile) * BM;
    // A staging: wave w stages rows w*16..w*16+15; per (row, half-stage) one
    // dwordx2 per lane = 512 B contiguous burst.
    const char* xg = (const char*)(x + (size_t)(row0 + w * 16) * P_DIM) + lane * 8;

    if (tile) __syncthreads();       // tile-0 epilogue S-reads done before Af reuse

    f32x4 acc[4];
#pragma unroll
    for (int t = 0; t < 4; ++t) acc[t] = (f32x4){0.f, 0.f, 0.f, 0.f};

    // prologue: B(0) (L2-hot on tile 1) then A(0)
    half8 bR[4];
#pragma unroll
    for (int i = 0; i < 4; ++i) bR[i] = *(const half8*)(bgG + (size_t)i * 1024);
    float2 pf[16];
#pragma unroll
    for (int i = 0; i < 16; ++i) pf[i] = *(const float2*)(xg + i * 4096);

    for (int h = 0; h < NH; ++h) {
      if (h) __syncthreads();        // prev half-stage fully consumed (A and B)
#pragma unroll
      for (int i = 0; i < 16; ++i)
        *(float2*)(Aw + i * 528) = pf[i];
#pragma unroll
      for (int i = 0; i < 4; ++i)
        *(half8*)(BsW + (size_t)i * 1024) = bR[i];
      __syncthreads();               // stage visible to all waves
      // issue next half-stage's loads (drained at next stage-top barrier)
      if (h + 1 < NH) {
        const size_t boff = (size_t)(h + 1) * 16384;
#pragma unroll
        for (int i = 0; i < 4; ++i)
          bR[i] = *(const half8*)(bgG + boff + (size_t)i * 1024);
#pragma unroll
        for (int i = 0; i < 16; ++i)
          pf[i] = *(const float2*)(xg + i * 4096 + (h + 1) * 512);
      }
      BODY(0);                       // chunk 2h   (A, B from LDS; no global waits)
      BODY(1);                       // chunk 2h+1
    }

    __syncthreads();                 // Af dead (as A-stage) from here on

    // acc -> S with bias (R12-verbatim). Tile (m,j): rows mrow+m*16+q*4+rr,
    // cols ncol+j*16+l15. D layout: col = lane&15, row = (lane>>4)*4 + reg.
#pragma unroll
    for (int m = 0; m < 2; ++m) {
#pragma unroll
      for (int j = 0; j < 2; ++j) {
        const int col = ncol + j * 16 + l15;
        float bias = biasC[col];
#pragma unroll
        for (int rr = 0; rr < 4; ++rr) {
          S[mrow + m * 16 + q * 4 + rr][col] = acc[m * 2 + j][rr] + bias;
        }
      }
    }
    __syncthreads();

    // Epilogue: experts [sub*16, sub*16+16) for row r2
    float lg[8];
#pragma unroll
    for (int k = 0; k < 8; ++k) lg[k] = S[r2][48 + k];
    float mx = lg[0];
#pragma unroll
    for (int k = 1; k < 8; ++k) mx = fmaxf(mx, lg[k]);
    float wk[8];
    float ssum = 0.f;
#pragma unroll
    for (int k = 0; k < 8; ++k) { wk[k] = expf(lg[k] - mx); ssum += wk[k]; }
    const float inv = 1.0f / ssum;

    float mix[16];
#pragma unroll
    for (int i = 0; i < 16; ++i) mix[i] = 0.f;

#pragma unroll
    for (int k = 0; k < 8; ++k) {
      float z[6];
#pragma unroll
      for (int j = 0; j < 6; ++j) {
        float tt = S[r2][k * 6 + j];
        float tc = fminf(fmaxf(tt, -0.25f), 0.25f);
        // smooth_step: -16 tc^3 + 3 tc + 0.5
        z[j] = fmaf(tc, fmaf(-16.0f * tc, tc, 3.0f), 0.5f);
      }
      float f4v = (sub & 1) ? z[4] : 1.0f - z[4];
      float f5v = (sub & 2) ? z[5] : 1.0f - z[5];
      float wf = wk[k] * inv * f4v * f5v;
      float t2[2], t4[4], t8[8], t16[16];
      t2[0] = 1.0f - z[0]; t2[1] = z[0];
#pragma unroll
      for (int i = 0; i < 2; ++i) { t4[i] = t2[i] * (1.0f - z[1]); t4[i + 2] = t2[i] * z[1]; }
#pragma unroll
      for (int i = 0; i < 4; ++i) { t8[i] = t4[i] * (1.0f - z[2]); t8[i + 4] = t4[i] * z[2]; }
#pragma unroll
      for (int i = 0; i < 8; ++i) { t16[i] = t8[i] * (1.0f - z[3]); t16[i + 8] = t8[i] * z[3]; }
#pragma unroll
      for (int i = 0; i < 16; ++i) mix[i] = fmaf(wf, t16[i], mix[i]);
    }

    float* op = out + (size_t)(row0 + r2) * 64 + sub * 16;
#pragma unroll
    for (int g = 0; g < 4; ++g) {
      float4 o;
      o.x = mix[4 * g + 0]; o.y = mix[4 * g + 1];
      o.z = mix[4 * g + 2]; o.w = mix[4 * g + 3];
      ((float4*)op)[g] = o;
    }
  }
}

extern "C" void kernel_launch(void* const* d_in, const int* in_sizes, int n_in,
                              void* d_out, int out_size, void* d_ws, size_t ws_size,
                              hipStream_t stream) {
  const float* x  = (const float*)d_in[0];
  const float* Gw = (const float*)d_in[1];
  const float* Gb = (const float*)d_in[2];
  const float* Ww = (const float*)d_in[3];
  const float* Wb = (const float*)d_in[4];
  float* out = (float*)d_out;

  _Float16* Wf2  = (_Float16*)d_ws;
  float*    bias = (float*)((char*)d_ws + 64 * P_DIM * sizeof(_Float16));

  const int B = in_sizes[0] / P_DIM;

  prep_weights<<<dim3(256), dim3(256), 0, stream>>>(Gw, Gb, Ww, Wb, Wf2, bias);
  fused_gate<<<dim3(B / (BM * 2)), dim3(256), 0, stream>>>(x, Wf2, bias, out);
  (void)n_in; (void)out_size; (void)ws_size;
}

// Round 17
// 64.648 us; speedup vs baseline: 1.2179x; 1.2179x over previous
//
#include <hip/hip_runtime.h>

typedef _Float16 half8 __attribute__((ext_vector_type(8)));
typedef _Float16 half4 __attribute__((ext_vector_type(4)));
typedef float f32x4 __attribute__((ext_vector_type(4)));

#define P_DIM 1024
#define BM 64
#define NS 4          // stages of K=256 floats each
#define AH_COLS 264   // 256 f16 + 8 pad = 528 B stride (R10/R12-proven bank pattern)

// FRAGMENT-MAJOR weights (proven R6/R10/R12): B-frag = 64 lanes x 16 B = 1 KB.
// Wf2[((S*4 + t)*64 + l)*8 + j] = W[t*16 + (l&15)][S*32 + (l>>4)*8 + j]
// rows 0-47 = W_w, 48-55 = G_w, 56-63 = 0.  S = k-step 0..31, t = n-tile 0..3.
__global__ __launch_bounds__(256) void prep_weights(
    const float* __restrict__ Gw, const float* __restrict__ Gb,
    const float* __restrict__ Ww, const float* __restrict__ Wb,
    _Float16* __restrict__ Wf2, float* __restrict__ biasC) {
  int i = blockIdx.x * 256 + threadIdx.x;   // 0 .. 65535
  int j = i & 7;
  int l = (i >> 3) & 63;
  int t = (i >> 9) & 3;
  int S = i >> 11;
  int row = t * 16 + (l & 15);
  int k   = S * 32 + (l >> 4) * 8 + j;
  float v = 0.0f;
  if (row < 48) v = Ww[row * P_DIM + k];
  else if (row < 56) v = Gw[(row - 48) * P_DIM + k];
  Wf2[i] = (_Float16)v;
  if (i < 64) {
    float bv = 0.0f;
    if (i < 48) bv = Wb[i];
    else if (i < 56) bv = Gb[i - 48];
    biasC[i] = bv;
  }
}

// R10-proven direct-L2 B loader for 32x32 wave tiles, global chunk c (K=64):
// dst[0]=frag(2c,tb) dst[1]=frag(2c+1,tb) dst[2]=frag(2c,tb+1) dst[3]=frag(2c+1,tb+1)
#define LOAD_B(dst, c) do { const char* p_ = bgw + (size_t)(c) * 8192; \
    dst[0] = *(const half8*)(p_);          dst[1] = *(const half8*)(p_ + 4096); \
    dst[2] = *(const half8*)(p_ + 1024);   dst[3] = *(const half8*)(p_ + 5120); \
  } while (0)

// Chunk cc (0..3 within a K=256 stage): A fragments straight from f16 LDS
// (no read-side cvt), 4 ds_read_b128 + 8 MFMA, R10-proven acc pairing.
#define BODY(bX, cc) do { \
    half8 h00_ = *(const half8*)(Ab0 + (cc) * 128); \
    half8 h01_ = *(const half8*)(Ab0 + (cc) * 128 + 64); \
    half8 h10_ = *(const half8*)(Ab1 + (cc) * 128); \
    half8 h11_ = *(const half8*)(Ab1 + (cc) * 128 + 64); \
    acc[0] = __builtin_amdgcn_mfma_f32_16x16x32_f16(h00_, bX[0], acc[0], 0, 0, 0); \
    acc[0] = __builtin_amdgcn_mfma_f32_16x16x32_f16(h01_, bX[1], acc[0], 0, 0, 0); \
    acc[1] = __builtin_amdgcn_mfma_f32_16x16x32_f16(h00_, bX[2], acc[1], 0, 0, 0); \
    acc[1] = __builtin_amdgcn_mfma_f32_16x16x32_f16(h01_, bX[3], acc[1], 0, 0, 0); \
    acc[2] = __builtin_amdgcn_mfma_f32_16x16x32_f16(h10_, bX[0], acc[2], 0, 0, 0); \
    acc[2] = __builtin_amdgcn_mfma_f32_16x16x32_f16(h11_, bX[1], acc[2], 0, 0, 0); \
    acc[3] = __builtin_amdgcn_mfma_f32_16x16x32_f16(h10_, bX[2], acc[3], 0, 0, 0); \
    acc[3] = __builtin_amdgcn_mfma_f32_16x16x32_f16(h11_, bX[3], acc[3], 0, 0, 0); \
  } while (0)

__global__ __launch_bounds__(256, 3) void fused_gate(
    const float* __restrict__ x, const _Float16* __restrict__ Wf2,
    const float* __restrict__ biasC, float* __restrict__ out) {
  // f16 A-stage (K=256 per stage); epilogue scratch S aliases it afterwards.
  // Typed f16-vector stores + half8 reads = the R11-proven-correct mechanism.
  __shared__ __align__(16) _Float16 Ah[BM][AH_COLS];   // 33792 B total LDS

  const int tid  = threadIdx.x;
  const int lane = tid & 63;
  const int w    = tid >> 6;        // wave id 0..3
  const int row0 = blockIdx.x * BM;
  const int l15  = lane & 15;
  const int q    = lane >> 4;

  // Wave tile (R10): rows [mrow, mrow+32), cols [ncol, ncol+32)
  const int mrow = (w >> 1) * 32;
  const int ncol = (w & 1) * 32;

  // A staging: wave w stages rows w*16..w*16+15. Per (row, stage): ONE float4
  // instr = 64 lanes x 16 B = 1 KB CONTIGUOUS — a full single-page burst.
  const char* xg = (const char*)(x + (size_t)(row0 + w * 16) * P_DIM) + lane * 16;
  // B (fragment-major, direct from L2/L1; R10-proven): this wave's n-tile pair
  const char* bgw = (const char*)Wf2 + lane * 16 + (size_t)(ncol / 16) * 1024;

  // LDS addresses. Write: row w*16+i, element 4*lane (byte 8*lane) — 2-way free.
  char* Aw = (char*)&Ah[w * 16][0] + lane * 8;                 // + i*528 per row
  // Read: element cc*64 + q*8 of rows mrow+l15 / +16 (byte cc*128 + q*16).
  const char* Ab0 = (const char*)&Ah[mrow + l15][0] + q * 16;
  const char* Ab1 = Ab0 + 16 * 528;

  f32x4 acc[4];
#pragma unroll
  for (int t = 0; t < 4; ++t) acc[t] = (f32x4){0.f, 0.f, 0.f, 0.f};

  // Prologue: B(0) oldest, then A stage 0 (16 x 1 KB bursts).
  half8 bA[4], bB[4];
  LOAD_B(bA, 0);
  float4 pf[16];
#pragma unroll
  for (int i = 0; i < 16; ++i) pf[i] = *(const float4*)(xg + i * 4096);

  for (int s = 0; s < NS; ++s) {
    if (s) __syncthreads();          // stage s-1 fully consumed
    // cvt f32->f16 at write; typed half4 stores (R11 mechanism)
#pragma unroll
    for (int i = 0; i < 16; ++i) {
      half4 hv;
      hv[0] = (_Float16)pf[i].x;
      hv[1] = (_Float16)pf[i].y;
      hv[2] = (_Float16)pf[i].z;
      hv[3] = (_Float16)pf[i].w;
      *(half4*)(Aw + i * 528) = hv;
    }
    __syncthreads();                 // stage visible to all waves
    const int c0 = 4 * s;
    // FIFO-ordered issue: B(c0+1) oldest; pf (HBM) issued after LB(bA,c0+2)
    // so BODY(bA,2)'s wait (bA older than pf) does NOT drain pf. pf is only
    // force-drained at BODY(bB,3) — a ~3-BODY window (~900+ cy) in flight.
    LOAD_B(bB, c0 + 1);
    BODY(bA, 0);                     // chunk c0
    LOAD_B(bA, c0 + 2);
    if (s + 1 < NS) {
#pragma unroll
      for (int i = 0; i < 16; ++i)
        pf[i] = *(const float4*)(xg + i * 4096 + (s + 1) * 1024);
    }
    BODY(bB, 1);                     // chunk c0+1
    LOAD_B(bB, c0 + 3);
    BODY(bA, 2);                     // chunk c0+2
    if (s + 1 < NS)
      LOAD_B(bA, c0 + 4);            // next stage's chunk 0
    BODY(bB, 3);                     // chunk c0+3
  }

  __syncthreads();                   // Ah dead (as A-stage) from here on
  float (*S)[65] = (float (*)[65])&Ah[0][0];   // epilogue scratch (16640 <= 33792)

  // acc -> S with bias (R10-verbatim). Tile (m,j): rows mrow+m*16+q*4+rr,
  // cols ncol+j*16+l15. D layout: col = lane&15, row = (lane>>4)*4 + reg.
#pragma unroll
  for (int m = 0; m < 2; ++m) {
#pragma unroll
    for (int j = 0; j < 2; ++j) {
      const int col = ncol + j * 16 + l15;
      float bias = biasC[col];
#pragma unroll
      for (int rr = 0; rr < 4; ++rr) {
        S[mrow + m * 16 + q * 4 + rr][col] = acc[m * 2 + j][rr] + bias;
      }
    }
  }
  __syncthreads();

  // Epilogue: 4 threads/row, experts [sub*16, sub*16+16)
  const int r2  = tid >> 2;
  const int sub = tid & 3;

  float lg[8];
#pragma unroll
  for (int k = 0; k < 8; ++k) lg[k] = S[r2][48 + k];
  float mx = lg[0];
#pragma unroll
  for (int k = 1; k < 8; ++k) mx = fmaxf(mx, lg[k]);
  float wk[8];
  float ssum = 0.f;
#pragma unroll
  for (int k = 0; k < 8; ++k) { wk[k] = expf(lg[k] - mx); ssum += wk[k]; }
  const float inv = 1.0f / ssum;

  float mix[16];
#pragma unroll
  for (int i = 0; i < 16; ++i) mix[i] = 0.f;

#pragma unroll
  for (int k = 0; k < 8; ++k) {
    float z[6];
#pragma unroll
    for (int j = 0; j < 6; ++j) {
      float tt = S[r2][k * 6 + j];
      float tc = fminf(fmaxf(tt, -0.25f), 0.25f);
      // smooth_step: -16 tc^3 + 3 tc + 0.5
      z[j] = fmaf(tc, fmaf(-16.0f * tc, tc, 3.0f), 0.5f);
    }
    float f4v = (sub & 1) ? z[4] : 1.0f - z[4];
    float f5v = (sub & 2) ? z[5] : 1.0f - z[5];
    float wf = wk[k] * inv * f4v * f5v;
    float t2[2], t4[4], t8[8], t16[16];
    t2[0] = 1.0f - z[0]; t2[1] = z[0];
#pragma unroll
    for (int i = 0; i < 2; ++i) { t4[i] = t2[i] * (1.0f - z[1]); t4[i + 2] = t2[i] * z[1]; }
#pragma unroll
    for (int i = 0; i < 4; ++i) { t8[i] = t4[i] * (1.0f - z[2]); t8[i + 4] = t4[i] * z[2]; }
#pragma unroll
    for (int i = 0; i < 8; ++i) { t16[i] = t8[i] * (1.0f - z[3]); t16[i + 8] = t8[i] * z[3]; }
#pragma unroll
    for (int i = 0; i < 16; ++i) mix[i] = fmaf(wf, t16[i], mix[i]);
  }

  float* op = out + (size_t)(row0 + r2) * 64 + sub * 16;
#pragma unroll
  for (int g = 0; g < 4; ++g) {
    float4 o;
    o.x = mix[4 * g + 0]; o.y = mix[4 * g + 1];
    o.z = mix[4 * g + 2]; o.w = mix[4 * g + 3];
    ((float4*)op)[g] = o;
  }
}

extern "C" void kernel_launch(void* const* d_in, const int* in_sizes, int n_in,
                              void* d_out, int out_size, void* d_ws, size_t ws_size,
                              hipStream_t stream) {
  const float* x  = (const float*)d_in[0];
  const float* Gw = (const float*)d_in[1];
  const float* Gb = (const float*)d_in[2];
  const float* Ww = (const float*)d_in[3];
  const float* Wb = (const float*)d_in[4];
  float* out = (float*)d_out;

  _Float16* Wf2  = (_Float16*)d_ws;
  float*    bias = (float*)((char*)d_ws + 64 * P_DIM * sizeof(_Float16));

  const int B = in_sizes[0] / P_DIM;

  prep_weights<<<dim3(256), dim3(256), 0, stream>>>(Gw, Gb, Ww, Wb, Wf2, bias);
  fused_gate<<<dim3(B / BM), dim3(256), 0, stream>>>(x, Wf2, bias, out);
  (void)n_in; (void)out_size; (void)ws_size;
}

// Round 18
// 57.611 us; speedup vs baseline: 1.3667x; 1.1221x over previous
//
#include <hip/hip_runtime.h>

typedef _Float16 half8 __attribute__((ext_vector_type(8)));
typedef float f32x4 __attribute__((ext_vector_type(4)));
typedef float f4 __attribute__((ext_vector_type(4)));

#define P_DIM 1024
#define BM 64
#define NH 8          // half-stages of K=128 floats each
#define AF_ROW 132    // LDS A row: 128 floats + 4 pad = 528 B stride (R10-proven)

// FRAGMENT-MAJOR weights (proven R6/R10): B-frag = 64 lanes x 16 B = 1 KB.
// Wf2[((S*4 + t)*64 + l)*8 + j] = W[t*16 + (l&15)][S*32 + (l>>4)*8 + j]
// rows 0-47 = W_w, 48-55 = G_w, 56-63 = 0.  S = k-step 0..31, t = n-tile 0..3.
__global__ __launch_bounds__(256) void prep_weights(
    const float* __restrict__ Gw, const float* __restrict__ Gb,
    const float* __restrict__ Ww, const float* __restrict__ Wb,
    _Float16* __restrict__ Wf2, float* __restrict__ biasC) {
  int i = blockIdx.x * 256 + threadIdx.x;   // 0 .. 65535
  int j = i & 7;
  int l = (i >> 3) & 63;
  int t = (i >> 9) & 3;
  int S = i >> 11;
  int row = t * 16 + (l & 15);
  int k   = S * 32 + (l >> 4) * 8 + j;
  float v = 0.0f;
  if (row < 48) v = Ww[row * P_DIM + k];
  else if (row < 56) v = Gw[(row - 48) * P_DIM + k];
  Wf2[i] = (_Float16)v;
  if (i < 64) {
    float bv = 0.0f;
    if (i < 48) bv = Wb[i];
    else if (i < 56) bv = Gb[i - 48];
    biasC[i] = bv;
  }
}

// BODY chunk cc (0/1 within half-stage): B frags from LDS, A from f32 LDS
// stage + cvt, 8 MFMA with R10's proven pairing.
#define BODY(cc) do { \
    half8 b0_ = *(const half8*)(BsR + (size_t)((2*(cc)  )*4    ) * 1024); \
    half8 b1_ = *(const half8*)(BsR + (size_t)((2*(cc)+1)*4    ) * 1024); \
    half8 b2_ = *(const half8*)(BsR + (size_t)((2*(cc)  )*4 + 1) * 1024); \
    half8 b3_ = *(const half8*)(BsR + (size_t)((2*(cc)+1)*4 + 1) * 1024); \
    f4 a0_[4], a1_[4]; \
    { const char* p0 = Abase0 + (cc) * 256; \
      a0_[0] = *(const f4*)(p0);       a0_[1] = *(const f4*)(p0 + 16); \
      a0_[2] = *(const f4*)(p0 + 128); a0_[3] = *(const f4*)(p0 + 144); \
      const char* p1 = Abase1 + (cc) * 256; \
      a1_[0] = *(const f4*)(p1);       a1_[1] = *(const f4*)(p1 + 16); \
      a1_[2] = *(const f4*)(p1 + 128); a1_[3] = *(const f4*)(p1 + 144); } \
    half8 h00_, h01_, h10_, h11_; \
    h00_[0]=(_Float16)a0_[0][0]; h00_[1]=(_Float16)a0_[0][1]; h00_[2]=(_Float16)a0_[0][2]; h00_[3]=(_Float16)a0_[0][3]; \
    h00_[4]=(_Float16)a0_[1][0]; h00_[5]=(_Float16)a0_[1][1]; h00_[6]=(_Float16)a0_[1][2]; h00_[7]=(_Float16)a0_[1][3]; \
    h01_[0]=(_Float16)a0_[2][0]; h01_[1]=(_Float16)a0_[2][1]; h01_[2]=(_Float16)a0_[2][2]; h01_[3]=(_Float16)a0_[2][3]; \
    h01_[4]=(_Float16)a0_[3][0]; h01_[5]=(_Float16)a0_[3][1]; h01_[6]=(_Float16)a0_[3][2]; h01_[7]=(_Float16)a0_[3][3]; \
    h10_[0]=(_Float16)a1_[0][0]; h10_[1]=(_Float16)a1_[0][1]; h10_[2]=(_Float16)a1_[0][2]; h10_[3]=(_Float16)a1_[0][3]; \
    h10_[4]=(_Float16)a1_[1][0]; h10_[5]=(_Float16)a1_[1][1]; h10_[6]=(_Float16)a1_[1][2]; h10_[7]=(_Float16)a1_[1][3]; \
    h11_[0]=(_Float16)a1_[2][0]; h11_[1]=(_Float16)a1_[2][1]; h11_[2]=(_Float16)a1_[2][2]; h11_[3]=(_Float16)a1_[2][3]; \
    h11_[4]=(_Float16)a1_[3][0]; h11_[5]=(_Float16)a1_[3][1]; h11_[6]=(_Float16)a1_[3][2]; h11_[7]=(_Float16)a1_[3][3]; \
    acc[0] = __builtin_amdgcn_mfma_f32_16x16x32_f16(h00_, b0_, acc[0], 0, 0, 0); \
    acc[0] = __builtin_amdgcn_mfma_f32_16x16x32_f16(h01_, b1_, acc[0], 0, 0, 0); \
    acc[1] = __builtin_amdgcn_mfma_f32_16x16x32_f16(h00_, b2_, acc[1], 0, 0, 0); \
    acc[1] = __builtin_amdgcn_mfma_f32_16x16x32_f16(h01_, b3_, acc[1], 0, 0, 0); \
    acc[2] = __builtin_amdgcn_mfma_f32_16x16x32_f16(h10_, b0_, acc[2], 0, 0, 0); \
    acc[2] = __builtin_amdgcn_mfma_f32_16x16x32_f16(h11_, b1_, acc[2], 0, 0, 0); \
    acc[3] = __builtin_amdgcn_mfma_f32_16x16x32_f16(h10_, b2_, acc[3], 0, 0, 0); \
    acc[3] = __builtin_amdgcn_mfma_f32_16x16x32_f16(h11_, b3_, acc[3], 0, 0, 0); \
  } while (0)

__global__ __launch_bounds__(256, 3) void fused_gate(
    const float* __restrict__ x, const _Float16* __restrict__ Wf2,
    const float* __restrict__ biasC, float* __restrict__ out) {
  // A-stage (f32); epilogue scratch S aliases it afterwards.
  __shared__ __align__(16) float Af[BM][AF_ROW];   // 33792 B
  // B-stage: one half-stage's 16 frags, single-buffered (barrier-ordered).
  __shared__ __align__(16) _Float16 BsH[8192];     // 16384 B  (total 50176)

  const int tid  = threadIdx.x;
  const int lane = tid & 63;
  const int w    = tid >> 6;        // wave id 0..3
  const int row0 = blockIdx.x * BM;
  const int l15  = lane & 15;
  const int q    = lane >> 4;

  // Wave tile (R10): rows [mrow, mrow+32), cols [ncol, ncol+32)
  const int mrow = (w >> 1) * 32;
  const int ncol = (w & 1) * 32;
  const int tb   = (w & 1) * 2;     // first n-tile of this wave's column pair

  // A staging: wave w stages rows w*16..w*16+15; per (row, half-stage) one
  // dwordx2 per lane = 512 B contiguous burst.
  const char* xg = (const char*)(x + (size_t)(row0 + w * 16) * P_DIM) + lane * 8;
  // B global: wave w loads frag-slots w*4..w*4+3 of each half-stage's 16 KB
  const char* bgG = (const char*)Wf2 + (size_t)(w * 4) * 1024 + lane * 16;

  char* Aw = (char*)&Af[w * 16][0] + lane * 8;                 // + i*528 per row
  const char* Abase0 = (const char*)&Af[mrow + l15][0] + q * 32;
  const char* Abase1 = Abase0 + 16 * 528;
  char* BsW = (char*)BsH + (size_t)(w * 4) * 1024 + lane * 16; // + i*1024
  const char* BsR = (const char*)BsH + (size_t)tb * 1024 + lane * 16;

  f32x4 acc[4];
#pragma unroll
  for (int t = 0; t < 4; ++t) acc[t] = (f32x4){0.f, 0.f, 0.f, 0.f};

  // prologue: A + B register-prefetch for half-stage 0
  float2 pf[16];
#pragma unroll
  for (int i = 0; i < 16; ++i) pf[i] = *(const float2*)(xg + i * 4096);
  half8 bR[4];
#pragma unroll
  for (int i = 0; i < 4; ++i) bR[i] = *(const half8*)(bgG + (size_t)i * 1024);

  for (int h = 0; h < NH; ++h) {
    if (h) __syncthreads();          // prev half-stage fully consumed (A and B)
    // stage A (f32) and B (half8 both sides) into LDS
#pragma unroll
    for (int i = 0; i < 16; ++i)
      *(float2*)(Aw + i * 528) = pf[i];
#pragma unroll
    for (int i = 0; i < 4; ++i)
      *(half8*)(BsW + (size_t)i * 1024) = bR[i];
    __syncthreads();                 // stage visible to all waves
    // issue next half-stage's loads (drained at next stage-top barrier)
    if (h + 1 < NH) {
      const size_t boff = (size_t)(h + 1) * 16384;
#pragma unroll
      for (int i = 0; i < 4; ++i)
        bR[i] = *(const half8*)(bgG + boff + (size_t)i * 1024);
#pragma unroll
      for (int i = 0; i < 16; ++i)
        pf[i] = *(const float2*)(xg + i * 4096 + (h + 1) * 512);
    }
    BODY(0);                         // chunk 2h   (A, B from LDS; no global waits)
    BODY(1);                         // chunk 2h+1
  }

  __syncthreads();                   // Af dead from here on
  float (*S)[65] = (float (*)[65])&Af[0][0];   // epilogue scratch aliases Af

  // acc -> S with bias. Tile (m,j): rows mrow+m*16+q*4+rr, cols ncol+j*16+l15.
  // D layout: col = lane&15, row = (lane>>4)*4 + reg.
#pragma unroll
  for (int m = 0; m < 2; ++m) {
#pragma unroll
    for (int j = 0; j < 2; ++j) {
      const int col = ncol + j * 16 + l15;
      float bias = biasC[col];
#pragma unroll
      for (int rr = 0; rr < 4; ++rr) {
        S[mrow + m * 16 + q * 4 + rr][col] = acc[m * 2 + j][rr] + bias;
      }
    }
  }
  __syncthreads();

  // Epilogue: 4 threads/row, experts [sub*16, sub*16+16)
  const int r2  = tid >> 2;
  const int sub = tid & 3;

  float lg[8];
#pragma unroll
  for (int k = 0; k < 8; ++k) lg[k] = S[r2][48 + k];
  float mx = lg[0];
#pragma unroll
  for (int k = 1; k < 8; ++k) mx = fmaxf(mx, lg[k]);
  float wk[8];
  float ssum = 0.f;
#pragma unroll
  for (int k = 0; k < 8; ++k) { wk[k] = expf(lg[k] - mx); ssum += wk[k]; }
  const float inv = 1.0f / ssum;

  float mix[16];
#pragma unroll
  for (int i = 0; i < 16; ++i) mix[i] = 0.f;

#pragma unroll
  for (int k = 0; k < 8; ++k) {
    float z[6];
#pragma unroll
    for (int j = 0; j < 6; ++j) {
      float tt = S[r2][k * 6 + j];
      float tc = fminf(fmaxf(tt, -0.25f), 0.25f);
      // smooth_step: -16 tc^3 + 3 tc + 0.5
      z[j] = fmaf(tc, fmaf(-16.0f * tc, tc, 3.0f), 0.5f);
    }
    float f4v = (sub & 1) ? z[4] : 1.0f - z[4];
    float f5v = (sub & 2) ? z[5] : 1.0f - z[5];
    float wf = wk[k] * inv * f4v * f5v;
    float t2[2], t4[4], t8[8], t16[16];
    t2[0] = 1.0f - z[0]; t2[1] = z[0];
#pragma unroll
    for (int i = 0; i < 2; ++i) { t4[i] = t2[i] * (1.0f - z[1]); t4[i + 2] = t2[i] * z[1]; }
#pragma unroll
    for (int i = 0; i < 4; ++i) { t8[i] = t4[i] * (1.0f - z[2]); t8[i + 4] = t4[i] * z[2]; }
#pragma unroll
    for (int i = 0; i < 8; ++i) { t16[i] = t8[i] * (1.0f - z[3]); t16[i + 8] = t8[i] * z[3]; }
#pragma unroll
    for (int i = 0; i < 16; ++i) mix[i] = fmaf(wf, t16[i], mix[i]);
  }

  float* op = out + (size_t)(row0 + r2) * 64 + sub * 16;
#pragma unroll
  for (int g = 0; g < 4; ++g) {
    float4 o;
    o.x = mix[4 * g + 0]; o.y = mix[4 * g + 1];
    o.z = mix[4 * g + 2]; o.w = mix[4 * g + 3];
    ((float4*)op)[g] = o;
  }
}

extern "C" void kernel_launch(void* const* d_in, const int* in_sizes, int n_in,
                              void* d_out, int out_size, void* d_ws, size_t ws_size,
                              hipStream_t stream) {
  const float* x  = (const float*)d_in[0];
  const float* Gw = (const float*)d_in[1];
  const float* Gb = (const float*)d_in[2];
  const float* Ww = (const float*)d_in[3];
  const float* Wb = (const float*)d_in[4];
  float* out = (float*)d_out;

  _Float16* Wf2  = (_Float16*)d_ws;
  float*    bias = (float*)((char*)d_ws + 64 * P_DIM * sizeof(_Float16));

  const int B = in_sizes[0] / P_DIM;

  prep_weights<<<dim3(256), dim3(256), 0, stream>>>(Gw, Gb, Ww, Wb, Wf2, bias);
  fused_gate<<<dim3(B / BM), dim3(256), 0, stream>>>(x, Wf2, bias, out);
  (void)n_in; (void)out_size; (void)ws_size;
}